// Round 7
// baseline (220.094 us; speedup 1.0000x reference)
//
#include <hip/hip_runtime.h>
#include <math.h>

#define NPTS    100000
#define NRAYS   4096
#define KTOP    10
#define KMER    12
#define CAP     128

// ---- spatial grid: 16^3 cells over [-0.8,0.8]^3, geometric boxes ----------
#define GCELLS  4096
#define RCAP    256               // per-ray run-list capacity (fallback if over)
#define DMARGIN 1e-3f             // conservative slack on d^2 bound (>=100x f32 ulp)
#define NB      64                // binning blocks
#define PPB     1568              // points per binning block (64*1568 >= NPTS)

// ---- theta (R3-proven): 512 blocks, 8 rays/block, 32768-pt sample ---------
#define TPAIR   4
#define NPART   64
#define TRAYS   8
#define TGRP    16

typedef float v2f __attribute__((ext_vector_type(2)));
typedef unsigned int u32;
typedef unsigned short u16;

static_assert(TGRP * 2048 <= NPTS, "theta sample within real points");
static_assert(NB * PPB >= NPTS, "binning covers all points");

__device__ __forceinline__ float4 make_center(const float* __restrict__ ro,
                                              const float* __restrict__ rd,
                                              int ray, float w) {
    float ox = ro[3 * ray + 0], oy = ro[3 * ray + 1], oz = ro[3 * ray + 2];
    float dx = rd[3 * ray + 0], dy = rd[3 * ray + 1], dz = rd[3 * ray + 2];
    float cx, cy, cz;
    {
#pragma clang fp contract(off)
        cx = ox + dx * 3.0f;
        cy = oy + dy * 3.0f;
        cz = oz + dz * 3.0f;
    }
    return make_float4(cx, cy, cz, w);
}

__device__ __forceinline__ float sigm(float x) { return 1.0f / (1.0f + expf(-x)); }

__device__ __forceinline__ float rfl(float x) {
    return __int_as_float(__builtin_amdgcn_readfirstlane(__float_as_int(x)));
}

__device__ __forceinline__ v2f score2(v2f px, v2f py, v2f pz, v2f pw,
                                      v2f rx, v2f ry, v2f rz) {
    v2f t = __builtin_elementwise_fma(pz, rz, pw);      // z,y,x order: bit-exact
    t = __builtin_elementwise_fma(py, ry, t);           // vs all prior rounds
    return __builtin_elementwise_fma(px, rx, t);
}

__device__ __forceinline__ unsigned long long mkkey(float sc, int id, bool v) {
    unsigned u = __float_as_uint(sc);
    u = (u & 0x80000000u) ? ~u : (u | 0x80000000u);    // order-preserving f32->u32
    unsigned long long k = ((unsigned long long)u << 32) | (unsigned)(~id);
    return v ? k : 0ull;                               // smaller id -> larger key
}

__device__ __forceinline__ int cellcoord(float x) {
    int v = (int)floorf((x + 0.8f) * 10.0f);           // 16 cells, edge 0.1
    return v < 0 ? 0 : (v > 15 ? 15 : v);              // clamp (edge boxes extend)
}

// ---------------------------------------------------------------------------
// theta_hist: R3-proven theta body (TRAYS=8, A/B pipelined groups), 512
// blocks; writes c4[ray]=(cx,cy,cz,theta). THEN blocks 0..63 run the R6
// LDS-private histogram (block-uniform branch -> barriers safe): cid16[i]
// + their mat row via plain coalesced stores. No global atomics anywhere
// (R5 lesson: hot-address global atomics = 24ns/op serial chain).
// ---------------------------------------------------------------------------
__global__ __launch_bounds__(256, 2) void theta_hist_kernel(const float* __restrict__ xyz,
                                                            const float* __restrict__ ro,
                                                            const float* __restrict__ rd,
                                                            float4* __restrict__ c4,
                                                            u32* __restrict__ mat,
                                                            u16* __restrict__ cid16) {
    __shared__ float4 rsh[TRAYS];
    __shared__ float  Msh[4][TRAYS][64];               // 8 KB, lane-stride 1
    __shared__ u32    h[GCELLS];                       // 16 KB (hist phase)
    const int tid = threadIdx.x, wave = tid >> 6, lane = tid & 63;
    const int rbase = blockIdx.x * TRAYS;

    if (tid < TRAYS) rsh[tid] = make_center(ro, rd, rbase + tid, 0.0f);
    __syncthreads();

    float4 rr[TRAYS];
#pragma unroll
    for (int r = 0; r < TRAYS; ++r) rr[r] = rsh[r];

    v2f M[TRAYS];
#pragma unroll
    for (int r = 0; r < TRAYS; ++r) M[r] = (v2f){-INFINITY, -INFINITY};

    v2f pxA[TPAIR], pyA[TPAIR], pzA[TPAIR], pwA[TPAIR];
    v2f pxB[TPAIR], pyB[TPAIR], pzB[TPAIR], pwB[TPAIR];

    auto loadg = [&](v2f* PX, v2f* PY, v2f* PZ, v2f* PW, int g) {
        const int id0 = g * 2048 + wave * 512 + lane;
#pragma unroll
        for (int u = 0; u < TPAIR; ++u) {
            int ia = id0 + (2 * u) * 64, ib = id0 + (2 * u + 1) * 64;
            float xa = xyz[3 * ia + 0], ya = xyz[3 * ia + 1], za = xyz[3 * ia + 2];
            float xb = xyz[3 * ib + 0], yb = xyz[3 * ib + 1], zb = xyz[3 * ib + 2];
            PX[u] = (v2f){xa, xb}; PY[u] = (v2f){ya, yb}; PZ[u] = (v2f){za, zb};
            PW[u] = (v2f){-0.5f * fmaf(xa, xa, fmaf(ya, ya, za * za)),
                          -0.5f * fmaf(xb, xb, fmaf(yb, yb, zb * zb))};
        }
    };
    auto computeg = [&](const v2f* PX, const v2f* PY, const v2f* PZ, const v2f* PW) {
#pragma unroll
        for (int r = 0; r < TRAYS; ++r) {
            const v2f rx = (v2f){rr[r].x, rr[r].x};
            const v2f ry = (v2f){rr[r].y, rr[r].y};
            const v2f rz = (v2f){rr[r].z, rr[r].z};
            v2f m = M[r];
#pragma unroll
            for (int u = 0; u < TPAIR; ++u)
                m = __builtin_elementwise_max(m, score2(PX[u], PY[u], PZ[u], PW[u], rx, ry, rz));
            M[r] = m;
        }
    };

    loadg(pxA, pyA, pzA, pwA, 0);
#pragma unroll 1
    for (int g = 0; g < TGRP; g += 2) {
        loadg(pxB, pyB, pzB, pwB, g + 1);
        computeg(pxA, pyA, pzA, pwA);
        if (g + 2 < TGRP) loadg(pxA, pyA, pzA, pwA, g + 2);
        computeg(pxB, pyB, pzB, pwB);
    }

#pragma unroll
    for (int r = 0; r < TRAYS; ++r)
        Msh[wave][r][lane] = fmaxf(M[r].x, M[r].y);
    __syncthreads();

    if (tid < TRAYS) {
        float vs[KTOP];
#pragma unroll
        for (int j = 0; j < KTOP; ++j) vs[j] = -INFINITY;
#pragma unroll 1
        for (int p = 0; p < NPART; ++p) {
            float v = fmaxf(fmaxf(Msh[0][tid][p], Msh[1][tid][p]),
                            fmaxf(Msh[2][tid][p], Msh[3][tid][p]));
#pragma unroll
            for (int t = KTOP - 1; t >= 1; --t) {
                bool up = v > vs[t - 1], here = v > vs[t];
                vs[t] = up ? vs[t - 1] : (here ? v : vs[t]);
            }
            vs[0] = fmaxf(vs[0], v);
        }
        float4 c = rsh[tid];
        c.w = vs[KTOP - 1];
        c4[rbase + tid] = c;
    }

    if (blockIdx.x < NB) {                             // hist phase, blocks 0..63
        const int b = blockIdx.x;
        for (int c = tid; c < GCELLS; c += 256) h[c] = 0;
        __syncthreads();                               // block-uniform: safe
        const int s = b * PPB, e = (s + PPB < NPTS) ? s + PPB : NPTS;
        for (int i = s + tid; i < e; i += 256) {
            float x = xyz[3 * i + 0], y = xyz[3 * i + 1], z = xyz[3 * i + 2];
            int cid = (cellcoord(x) << 8) | (cellcoord(y) << 4) | cellcoord(z);
            cid16[i] = (u16)cid;
            atomicAdd(&h[cid], 1u);                    // LDS atomic only
        }
        __syncthreads();
        u32* row = mat + (size_t)b * GCELLS;
        for (int c = tid; c < GCELLS; c += 256) row[c] = h[c];
    }
}

// ---------------------------------------------------------------------------
// meta: colsum + prefix + offs fused, 1 block (saves 2 launches). LDS-staged:
// cc[c] = counts -> (prefix) -> starts; offs walks mat columns in-place so
// mat[b][c] becomes the scatter base for (block b, cell c). No atomics.
// ---------------------------------------------------------------------------
__global__ __launch_bounds__(256) void meta_kernel(u32* __restrict__ mat,
                                                   u32* __restrict__ cellstart) {
    __shared__ u32 cc[GCELLS];
    __shared__ u32 wsum[4];
    const int tid = threadIdx.x, wave = tid >> 6, lane = tid & 63;

    for (int c = tid; c < GCELLS; c += 256) {          // colsum (coalesced rows)
        u32 s = 0;
#pragma unroll 4
        for (int b = 0; b < NB; ++b) s += mat[(size_t)b * GCELLS + c];
        cc[c] = s;
    }
    __syncthreads();

    const int base = tid * 16;                         // prefix (R6-proven body)
    u32 loc[16]; u32 s = 0;
#pragma unroll
    for (int k = 0; k < 16; ++k) { loc[k] = cc[base + k]; s += loc[k]; }
    u32 v = s;
#pragma unroll
    for (int off = 1; off < 64; off <<= 1) {
        u32 o = __shfl_up(v, off);
        if (lane >= off) v += o;
    }
    if (lane == 63) wsum[wave] = v;
    __syncthreads();
    u32 woff = 0;
    for (int w = 0; w < 4; ++w) if (w < wave) woff += wsum[w];
    u32 run = woff + v - s;                            // exclusive start
#pragma unroll
    for (int k = 0; k < 16; ++k) {
        cellstart[base + k] = run;
        cc[base + k] = run;                            // own range only: safe
        run += loc[k];
    }
    if (tid == 255) cellstart[4096] = run;             // == NPTS
    __syncthreads();

#pragma unroll 1
    for (int j = 0; j < 16; ++j) {                     // offs (coalesced rows)
        const int c = tid + 256 * j;
        u32 r2 = cc[c];
#pragma unroll 4
        for (int b = 0; b < NB; ++b) {
            size_t idx = (size_t)b * GCELLS + c;
            u32 t = mat[idx];
            mat[idx] = r2;
            r2 += t;
        }
    }
}

// ---------------------------------------------------------------------------
// scatter: block b loads its offset row into an LDS cursor, then places its
// own PPB points via LDS atomics only. Order within a cell is arbitrary —
// downstream is order-invariant (R5/R6 verified, absmax=0).
// ---------------------------------------------------------------------------
__global__ __launch_bounds__(256) void scatter_kernel(const float* __restrict__ xyz,
                                                      const u16* __restrict__ cid16,
                                                      const u32* __restrict__ mat,
                                                      float4* __restrict__ pts4,
                                                      int* __restrict__ pid) {
    __shared__ u32 cur[GCELLS];
    const int b = blockIdx.x, tid = threadIdx.x;
    const u32* row = mat + (size_t)b * GCELLS;
    for (int c = tid; c < GCELLS; c += 256) cur[c] = row[c];
    __syncthreads();
    const int s = b * PPB, e = (s + PPB < NPTS) ? s + PPB : NPTS;
    for (int i = s + tid; i < e; i += 256) {
        int cid = cid16[i];
        u32 dst = atomicAdd(&cur[cid], 1u);
        float x = xyz[3 * i + 0], y = xyz[3 * i + 1], z = xyz[3 * i + 2];
        pts4[dst] = make_float4(x, y, z, -0.5f * fmaf(x, x, fmaf(y, y, z * z)));
        pid[dst] = i;
    }
}

// ---------------------------------------------------------------------------
// scanmerge: R6 scan (geometric-box pruning via separable per-axis d^2
// tables, contiguous cell runs, exact fma emit test, full-sweep fallback)
// FUSED with the proven merge body running directly on lbuf in LDS — no
// cand/cnt global round-trip, one less dispatch. Entries >= lcnt are
// garbage but masked by mkkey(valid=false); merge is order-invariant
// (unique keys + f64 re-rank; R5/R6 absmax=0).
// ---------------------------------------------------------------------------
__global__ __launch_bounds__(256) void scanmerge_kernel(const float4* __restrict__ pts4,
                                                        const int* __restrict__ pid,
                                                        const u32* __restrict__ cellstart,
                                                        const float4* __restrict__ c4,
                                                        const float* __restrict__ ro,
                                                        const float* __restrict__ rd,
                                                        const float* __restrict__ xyz,
                                                        const float* __restrict__ fdc,
                                                        const float* __restrict__ opac,
                                                        float* __restrict__ out) {
    __shared__ u32    runS[4][RCAP], runE[4][RCAP];
    __shared__ float2 lbuf[4][CAP];
    __shared__ float  axd2[4][3][16];                  // per-wave d^2 tables
    __shared__ int    nrun[4], lcnt[4];
    const int tid = threadIdx.x, wv = tid >> 6, lane = tid & 63;
    const int ray = blockIdx.x * 4 + wv;

    float4 q = c4[ray];
    const float cx = rfl(q.x), cy = rfl(q.y), cz = rfl(q.z), th = rfl(q.w);
    const float limit = fmaf(cx, cx, fmaf(cy, cy, cz * cz)) - 2.0f * th + DMARGIN;

    if (lane == 0) { nrun[wv] = 0; lcnt[wv] = 0; }
    if (lane < 48) {                                   // build per-axis tables
        const int ax = lane >> 4, i = lane & 15;
        const float cc = (ax == 0) ? cx : ((ax == 1) ? cy : cz);
        const float lo = (i == 0)  ? -3.0e38f : -0.8f + 0.1f * (float)i;
        const float hi = (i == 15) ?  3.0e38f : -0.8f + 0.1f * (float)(i + 1);
        const float d = fmaxf(fmaxf(lo - cc, cc - hi), 0.0f);
        axd2[wv][ax][i] = d * d;
    }
    __syncthreads();

#pragma unroll 1
    for (int cc4 = 0; cc4 < 4; ++cc4) {                // 4 columns per lane
        const int col = lane + cc4 * 64;               // col = ix*16 + iy
        const float base2 = axd2[wv][0][col >> 4] + axd2[wv][1][col & 15];
        u32 mask = 0;
        if (base2 <= limit) {
#pragma unroll
            for (int iz = 0; iz < 16; ++iz)
                mask |= (base2 + axd2[wv][2][iz] <= limit) ? (1u << iz) : 0u;
        }
        const int colbase = col << 4;
        while (mask) {                                 // contiguous cell runs
            int lo = __ffs(mask) - 1;
            u32 t = mask >> lo;
            int len = __ffs(~t) - 1;                   // t<=0xFFFF -> ~t != 0
            mask &= ~(((1u << len) - 1u) << lo);
            u32 s = cellstart[colbase + lo];
            u32 e = cellstart[colbase + lo + len];     // <= 4096 sentinel
            if (e > s) {
                int slot = atomicAdd(&nrun[wv], 1);
                if (slot < RCAP) { runS[wv][slot] = s; runE[wv][slot] = e; }
            }
        }
    }
    __syncthreads();

    int NR = nrun[wv];
    const bool fb = NR > RCAP;                         // overflow -> full sweep
    if (fb) NR = 1;
#pragma unroll 1
    for (int ri = 0; ri < NR; ++ri) {
        u32 s = fb ? 0u : runS[wv][ri];
        u32 e = fb ? (u32)NPTS : runE[wv][ri];
        for (u32 j = s + lane; j < e; j += 64) {
            float4 p = pts4[j];
            float sc = fmaf(p.x, cx, fmaf(p.y, cy, fmaf(p.z, cz, p.w)));
            if (sc >= th) {
                int slot = atomicAdd(&lcnt[wv], 1);
                if (slot < CAP) lbuf[wv][slot] = make_float2(sc, __int_as_float(pid[j]));
            }
        }
    }
    __syncthreads();

    // ---- merge phase (proven body, candidates from LDS) -------------------
    int n = lcnt[wv];
    n = n < CAP ? n : CAP;

    float2 e0 = lbuf[wv][lane];
    float2 e1 = lbuf[wv][64 + lane];
    int id0 = __float_as_int(e0.y), id1 = __float_as_int(e1.y);

    unsigned long long k0 = mkkey(e0.x, id0, lane < n);
    unsigned long long k1 = mkkey(e1.x, id1, lane + 64 < n);

    int sel = -1;
    unsigned long long kl = k0 > k1 ? k0 : k1;
#pragma unroll
    for (int j = 0; j < KMER; ++j) {
        unsigned long long m = kl;
#pragma unroll
        for (int off = 1; off < 64; off <<= 1) {
            unsigned long long o = __shfl_xor(m, off);
            m = m > o ? m : o;
        }
        bool win = (kl == m) && (m != 0ull);
        int wid = (k0 >= k1) ? id0 : id1;
        unsigned long long wmask = __ballot(win);
        int wl = __ffsll(wmask) - 1;
        int bid = __shfl(wid, wl & 63);
        if (m == 0ull) bid = -1;
        if (lane == j) sel = bid;
        if (win) {
            if (k0 >= k1) k0 = 0ull; else k1 = 0ull;
            kl = k0 > k1 ? k0 : k1;
        }
    }

    float ox = ro[3 * ray + 0], oy = ro[3 * ray + 1], oz = ro[3 * ray + 2];
    float dx = rd[3 * ray + 0], dy = rd[3 * ray + 1], dz = rd[3 * ray + 2];
    float cxf, cyf, czf;
    {
#pragma clang fp contract(off)
        cxf = ox + dx * 3.0f;
        cyf = oy + dy * 3.0f;
        czf = oz + dz * 3.0f;
    }
    double Cx = (double)cxf, Cy = (double)cyf, Cz = (double)czf;
    double cn = Cx * Cx + Cy * Cy + Cz * Cz;

    bool valid = (lane < KMER) && (sel >= 0);
    int pidv = valid ? sel : 0;
    double X = (double)xyz[3 * pidv + 0];
    double Y = (double)xyz[3 * pidv + 1];
    double Z = (double)xyz[3 * pidv + 2];
    double sq = valid ? (cn + (X * X + Y * Y + Z * Z) - 2.0 * (Cx * X + Cy * Y + Cz * Z))
                      : (double)INFINITY;
    int cid = valid ? sel : 0x7fffffff;

    int rank = 0;
#pragma unroll
    for (int k = 0; k < KMER; ++k) {
        double sk = __shfl(sq, k);
        int    ik = __shfl(cid, k);
        if ((sk < sq) || (sk == sq && ik < cid)) ++rank;
    }

    bool take = valid && (rank < KTOP);
    float w = 0.0f, rr = 0.0f, gg = 0.0f, bb = 0.0f;
    if (take) {
        float dd = sqrtf(fmaxf((float)sq, 0.0f));
        w  = expf(-0.1f * dd) * sigm(opac[pidv]);
        rr = w * sigm(fdc[3 * pidv + 0]);
        gg = w * sigm(fdc[3 * pidv + 1]);
        bb = w * sigm(fdc[3 * pidv + 2]);
    }
#pragma unroll
    for (int off = 1; off < 64; off <<= 1) {
        w  += __shfl_xor(w,  off);
        rr += __shfl_xor(rr, off);
        gg += __shfl_xor(gg, off);
        bb += __shfl_xor(bb, off);
    }
    if (lane == 0) {
        float inv = 1.0f / (w + 1e-8f);
        out[3 * ray + 0] = rr * inv;
        out[3 * ray + 1] = gg * inv;
        out[3 * ray + 2] = bb * inv;
    }
}

// ---------------------------------------------------------------------------
extern "C" void kernel_launch(void* const* d_in, const int* in_sizes, int n_in,
                              void* d_out, int out_size, void* d_ws, size_t ws_size,
                              hipStream_t stream) {
    const float* rays_o = (const float*)d_in[0];
    const float* rays_d = (const float*)d_in[1];
    const float* xyz    = (const float*)d_in[2];
    const float* fdc    = (const float*)d_in[3];
    const float* opac   = (const float*)d_in[4];
    float* out = (float*)d_out;

    // ws layout (16B-aligned chain), total ~3.3 MB:
    char* p = (char*)d_ws;
    float4* c4       = (float4*)p;  p += (size_t)NRAYS  * 16;          // 64 KB
    float4* pts4     = (float4*)p;  p += (size_t)(NPTS + 64) * 16;     // 1.6 MB
    u32*    mat      = (u32*)p;     p += (size_t)NB * GCELLS * 4;      // 1 MB
    u32*    cellstart= (u32*)p;     p += (size_t)4112 * 4;             // 16.4 KB
    int*    pid      = (int*)p;     p += (size_t)(NPTS + 64) * 4;      // 400 KB
    u16*    cid16    = (u16*)p;     p += (size_t)(NPTS + 64) * 2;      // 200 KB

    theta_hist_kernel<<<NRAYS / TRAYS, 256, 0, stream>>>(xyz, rays_o, rays_d, c4, mat, cid16);
    meta_kernel<<<1, 256, 0, stream>>>(mat, cellstart);
    scatter_kernel<<<NB, 256, 0, stream>>>(xyz, cid16, mat, pts4, pid);
    scanmerge_kernel<<<NRAYS / 4, 256, 0, stream>>>(pts4, pid, cellstart, c4,
                                                    rays_o, rays_d, xyz, fdc, opac, out);
}

// Round 8
// 141.027 us; speedup vs baseline: 1.5607x; 1.5607x over previous
//
#include <hip/hip_runtime.h>
#include <math.h>

#define NPTS    100000
#define NRAYS   4096
#define KTOP    10
#define KMER    12
#define CAP     128

// ---- spatial grid: 16^3 cells over [-0.8,0.8]^3, geometric boxes ----------
#define GCELLS  4096
#define RCAP    256               // per-ray run-list capacity (fallback if over)
#define DMARGIN 1e-3f             // conservative slack on d^2 bound (>=100x f32 ulp)
#define NB      64                // binning blocks
#define PPB     1568              // points per binning block (64*1568 >= NPTS)

// ---- theta (R3-proven): 512 blocks, 8 rays/block, 32768-pt sample ---------
#define TPAIR   4
#define NPART   64
#define TRAYS   8
#define TGRP    16

typedef float v2f __attribute__((ext_vector_type(2)));
typedef unsigned int u32;
typedef unsigned short u16;

static_assert(TGRP * 2048 <= NPTS, "theta sample within real points");
static_assert(NB * PPB >= NPTS, "binning covers all points");

__device__ __forceinline__ float4 make_center(const float* __restrict__ ro,
                                              const float* __restrict__ rd,
                                              int ray, float w) {
    float ox = ro[3 * ray + 0], oy = ro[3 * ray + 1], oz = ro[3 * ray + 2];
    float dx = rd[3 * ray + 0], dy = rd[3 * ray + 1], dz = rd[3 * ray + 2];
    float cx, cy, cz;
    {
#pragma clang fp contract(off)
        cx = ox + dx * 3.0f;
        cy = oy + dy * 3.0f;
        cz = oz + dz * 3.0f;
    }
    return make_float4(cx, cy, cz, w);
}

__device__ __forceinline__ float sigm(float x) { return 1.0f / (1.0f + expf(-x)); }

__device__ __forceinline__ float rfl(float x) {
    return __int_as_float(__builtin_amdgcn_readfirstlane(__float_as_int(x)));
}

__device__ __forceinline__ v2f score2(v2f px, v2f py, v2f pz, v2f pw,
                                      v2f rx, v2f ry, v2f rz) {
    v2f t = __builtin_elementwise_fma(pz, rz, pw);      // z,y,x order: bit-exact
    t = __builtin_elementwise_fma(py, ry, t);           // vs all prior rounds
    return __builtin_elementwise_fma(px, rx, t);
}

__device__ __forceinline__ unsigned long long mkkey(float sc, int id, bool v) {
    unsigned u = __float_as_uint(sc);
    u = (u & 0x80000000u) ? ~u : (u | 0x80000000u);    // order-preserving f32->u32
    unsigned long long k = ((unsigned long long)u << 32) | (unsigned)(~id);
    return v ? k : 0ull;                               // smaller id -> larger key
}

__device__ __forceinline__ int cellcoord(float x) {
    int v = (int)floorf((x + 0.8f) * 10.0f);           // 16 cells, edge 0.1
    return v < 0 ? 0 : (v > 15 ? 15 : v);              // clamp (edge boxes extend)
}

// ---------------------------------------------------------------------------
// theta_hist: R3-proven theta body (TRAYS=8, A/B pipelined groups), 512
// blocks; writes c4[ray]=(cx,cy,cz,theta). THEN blocks 0..63 run the R6
// LDS-private histogram (block-uniform branch -> barriers safe): cid16[i]
// + their mat row via plain coalesced stores. No global atomics anywhere
// (R5 lesson: hot-address global atomics = 24ns/op serial chain).
// ---------------------------------------------------------------------------
__global__ __launch_bounds__(256, 2) void theta_hist_kernel(const float* __restrict__ xyz,
                                                            const float* __restrict__ ro,
                                                            const float* __restrict__ rd,
                                                            float4* __restrict__ c4,
                                                            u32* __restrict__ mat,
                                                            u16* __restrict__ cid16) {
    __shared__ float4 rsh[TRAYS];
    __shared__ float  Msh[4][TRAYS][64];               // 8 KB, lane-stride 1
    __shared__ u32    h[GCELLS];                       // 16 KB (hist phase)
    const int tid = threadIdx.x, wave = tid >> 6, lane = tid & 63;
    const int rbase = blockIdx.x * TRAYS;

    if (tid < TRAYS) rsh[tid] = make_center(ro, rd, rbase + tid, 0.0f);
    __syncthreads();

    float4 rr[TRAYS];
#pragma unroll
    for (int r = 0; r < TRAYS; ++r) rr[r] = rsh[r];

    v2f M[TRAYS];
#pragma unroll
    for (int r = 0; r < TRAYS; ++r) M[r] = (v2f){-INFINITY, -INFINITY};

    v2f pxA[TPAIR], pyA[TPAIR], pzA[TPAIR], pwA[TPAIR];
    v2f pxB[TPAIR], pyB[TPAIR], pzB[TPAIR], pwB[TPAIR];

    auto loadg = [&](v2f* PX, v2f* PY, v2f* PZ, v2f* PW, int g) {
        const int id0 = g * 2048 + wave * 512 + lane;
#pragma unroll
        for (int u = 0; u < TPAIR; ++u) {
            int ia = id0 + (2 * u) * 64, ib = id0 + (2 * u + 1) * 64;
            float xa = xyz[3 * ia + 0], ya = xyz[3 * ia + 1], za = xyz[3 * ia + 2];
            float xb = xyz[3 * ib + 0], yb = xyz[3 * ib + 1], zb = xyz[3 * ib + 2];
            PX[u] = (v2f){xa, xb}; PY[u] = (v2f){ya, yb}; PZ[u] = (v2f){za, zb};
            PW[u] = (v2f){-0.5f * fmaf(xa, xa, fmaf(ya, ya, za * za)),
                          -0.5f * fmaf(xb, xb, fmaf(yb, yb, zb * zb))};
        }
    };
    auto computeg = [&](const v2f* PX, const v2f* PY, const v2f* PZ, const v2f* PW) {
#pragma unroll
        for (int r = 0; r < TRAYS; ++r) {
            const v2f rx = (v2f){rr[r].x, rr[r].x};
            const v2f ry = (v2f){rr[r].y, rr[r].y};
            const v2f rz = (v2f){rr[r].z, rr[r].z};
            v2f m = M[r];
#pragma unroll
            for (int u = 0; u < TPAIR; ++u)
                m = __builtin_elementwise_max(m, score2(PX[u], PY[u], PZ[u], PW[u], rx, ry, rz));
            M[r] = m;
        }
    };

    loadg(pxA, pyA, pzA, pwA, 0);
#pragma unroll 1
    for (int g = 0; g < TGRP; g += 2) {
        loadg(pxB, pyB, pzB, pwB, g + 1);
        computeg(pxA, pyA, pzA, pwA);
        if (g + 2 < TGRP) loadg(pxA, pyA, pzA, pwA, g + 2);
        computeg(pxB, pyB, pzB, pwB);
    }

#pragma unroll
    for (int r = 0; r < TRAYS; ++r)
        Msh[wave][r][lane] = fmaxf(M[r].x, M[r].y);
    __syncthreads();

    if (tid < TRAYS) {
        float vs[KTOP];
#pragma unroll
        for (int j = 0; j < KTOP; ++j) vs[j] = -INFINITY;
#pragma unroll 1
        for (int p = 0; p < NPART; ++p) {
            float v = fmaxf(fmaxf(Msh[0][tid][p], Msh[1][tid][p]),
                            fmaxf(Msh[2][tid][p], Msh[3][tid][p]));
#pragma unroll
            for (int t = KTOP - 1; t >= 1; --t) {
                bool up = v > vs[t - 1], here = v > vs[t];
                vs[t] = up ? vs[t - 1] : (here ? v : vs[t]);
            }
            vs[0] = fmaxf(vs[0], v);
        }
        float4 c = rsh[tid];
        c.w = vs[KTOP - 1];
        c4[rbase + tid] = c;
    }

    if (blockIdx.x < NB) {                             // hist phase, blocks 0..63
        const int b = blockIdx.x;
        for (int c = tid; c < GCELLS; c += 256) h[c] = 0;
        __syncthreads();                               // block-uniform: safe
        const int s = b * PPB, e = (s + PPB < NPTS) ? s + PPB : NPTS;
        for (int i = s + tid; i < e; i += 256) {
            float x = xyz[3 * i + 0], y = xyz[3 * i + 1], z = xyz[3 * i + 2];
            int cid = (cellcoord(x) << 8) | (cellcoord(y) << 4) | cellcoord(z);
            cid16[i] = (u16)cid;
            atomicAdd(&h[cid], 1u);                    // LDS atomic only
        }
        __syncthreads();
        u32* row = mat + (size_t)b * GCELLS;
        for (int c = tid; c < GCELLS; c += 256) row[c] = h[c];
    }
}

// ---------------------------------------------------------------------------
// colprefix: thread-per-cell-column (16 blocks x 256 thr = 4096 threads),
// single pass: mat[b][c] <- exclusive within-column prefix; colsum[c] <-
// column total. Structurally R6's proven offs_kernel (never a hot dispatch)
// + fused colsum. Replaces R7's 1-block meta whose serial chain was 89us at
// 0.04% busy (1024-deep dependent global RMW on one CU).
// ---------------------------------------------------------------------------
__global__ __launch_bounds__(256) void colprefix_kernel(u32* __restrict__ mat,
                                                        u32* __restrict__ colsum) {
    const int c = blockIdx.x * 256 + threadIdx.x;      // 16 blocks
    u32 run = 0;
#pragma unroll 4
    for (int b = 0; b < NB; ++b) {
        size_t idx = (size_t)b * GCELLS + c;
        u32 t = mat[idx];                              // coalesced across lanes
        mat[idx] = run;
        run += t;
    }
    colsum[c] = run;
}

// ---------------------------------------------------------------------------
// prefix: exclusive prefix over 4096 cell counts (1 block, R6-proven body).
// Sentinel cellstart[4096] = NPTS.
// ---------------------------------------------------------------------------
__global__ __launch_bounds__(256) void prefix_kernel(const u32* __restrict__ cellcnt,
                                                     u32* __restrict__ cellstart) {
    __shared__ u32 wsum[4];
    const int tid = threadIdx.x, wave = tid >> 6, lane = tid & 63;
    const int base = tid * 16;
    u32 loc[16]; u32 s = 0;
#pragma unroll
    for (int k = 0; k < 16; ++k) { loc[k] = cellcnt[base + k]; s += loc[k]; }
    u32 v = s;
#pragma unroll
    for (int off = 1; off < 64; off <<= 1) {
        u32 o = __shfl_up(v, off);
        if (lane >= off) v += o;
    }
    if (lane == 63) wsum[wave] = v;
    __syncthreads();
    u32 woff = 0;
    for (int w = 0; w < 4; ++w) if (w < wave) woff += wsum[w];
    u32 run = woff + v - s;                            // exclusive start
#pragma unroll
    for (int k = 0; k < 16; ++k) {
        cellstart[base + k] = run;
        run += loc[k];
    }
    if (tid == 255) cellstart[4096] = run;             // == NPTS
}

// ---------------------------------------------------------------------------
// scatter: block b's cursor = its within-column prefix row + cellstart
// (one add at LDS-load time — saves the second mat walk R7's meta did).
// LDS atomics only; order within a cell arbitrary (downstream order-
// invariant, R5/R6 verified absmax=0).
// ---------------------------------------------------------------------------
__global__ __launch_bounds__(256) void scatter_kernel(const float* __restrict__ xyz,
                                                      const u16* __restrict__ cid16,
                                                      const u32* __restrict__ mat,
                                                      const u32* __restrict__ cellstart,
                                                      float4* __restrict__ pts4,
                                                      int* __restrict__ pid) {
    __shared__ u32 cur[GCELLS];
    const int b = blockIdx.x, tid = threadIdx.x;
    const u32* row = mat + (size_t)b * GCELLS;
    for (int c = tid; c < GCELLS; c += 256) cur[c] = row[c] + cellstart[c];
    __syncthreads();
    const int s = b * PPB, e = (s + PPB < NPTS) ? s + PPB : NPTS;
    for (int i = s + tid; i < e; i += 256) {
        int cid = cid16[i];
        u32 dst = atomicAdd(&cur[cid], 1u);
        float x = xyz[3 * i + 0], y = xyz[3 * i + 1], z = xyz[3 * i + 2];
        pts4[dst] = make_float4(x, y, z, -0.5f * fmaf(x, x, fmaf(y, y, z * z)));
        pid[dst] = i;
    }
}

// ---------------------------------------------------------------------------
// scanmerge: R6 scan (geometric-box pruning via separable per-axis d^2
// tables, contiguous cell runs, exact fma emit test, full-sweep fallback)
// FUSED with the proven merge body running directly on lbuf in LDS — no
// cand/cnt global round-trip. Entries >= lcnt are garbage but masked by
// mkkey(valid=false); merge is order-invariant (unique keys + f64 re-rank;
// R5/R6/R7 absmax=0).
// ---------------------------------------------------------------------------
__global__ __launch_bounds__(256) void scanmerge_kernel(const float4* __restrict__ pts4,
                                                        const int* __restrict__ pid,
                                                        const u32* __restrict__ cellstart,
                                                        const float4* __restrict__ c4,
                                                        const float* __restrict__ ro,
                                                        const float* __restrict__ rd,
                                                        const float* __restrict__ xyz,
                                                        const float* __restrict__ fdc,
                                                        const float* __restrict__ opac,
                                                        float* __restrict__ out) {
    __shared__ u32    runS[4][RCAP], runE[4][RCAP];
    __shared__ float2 lbuf[4][CAP];
    __shared__ float  axd2[4][3][16];                  // per-wave d^2 tables
    __shared__ int    nrun[4], lcnt[4];
    const int tid = threadIdx.x, wv = tid >> 6, lane = tid & 63;
    const int ray = blockIdx.x * 4 + wv;

    float4 q = c4[ray];
    const float cx = rfl(q.x), cy = rfl(q.y), cz = rfl(q.z), th = rfl(q.w);
    const float limit = fmaf(cx, cx, fmaf(cy, cy, cz * cz)) - 2.0f * th + DMARGIN;

    if (lane == 0) { nrun[wv] = 0; lcnt[wv] = 0; }
    if (lane < 48) {                                   // build per-axis tables
        const int ax = lane >> 4, i = lane & 15;
        const float cc = (ax == 0) ? cx : ((ax == 1) ? cy : cz);
        const float lo = (i == 0)  ? -3.0e38f : -0.8f + 0.1f * (float)i;
        const float hi = (i == 15) ?  3.0e38f : -0.8f + 0.1f * (float)(i + 1);
        const float d = fmaxf(fmaxf(lo - cc, cc - hi), 0.0f);
        axd2[wv][ax][i] = d * d;
    }
    __syncthreads();

#pragma unroll 1
    for (int cc4 = 0; cc4 < 4; ++cc4) {                // 4 columns per lane
        const int col = lane + cc4 * 64;               // col = ix*16 + iy
        const float base2 = axd2[wv][0][col >> 4] + axd2[wv][1][col & 15];
        u32 mask = 0;
        if (base2 <= limit) {
#pragma unroll
            for (int iz = 0; iz < 16; ++iz)
                mask |= (base2 + axd2[wv][2][iz] <= limit) ? (1u << iz) : 0u;
        }
        const int colbase = col << 4;
        while (mask) {                                 // contiguous cell runs
            int lo = __ffs(mask) - 1;
            u32 t = mask >> lo;
            int len = __ffs(~t) - 1;                   // t<=0xFFFF -> ~t != 0
            mask &= ~(((1u << len) - 1u) << lo);
            u32 s = cellstart[colbase + lo];
            u32 e = cellstart[colbase + lo + len];     // <= 4096 sentinel
            if (e > s) {
                int slot = atomicAdd(&nrun[wv], 1);
                if (slot < RCAP) { runS[wv][slot] = s; runE[wv][slot] = e; }
            }
        }
    }
    __syncthreads();

    int NR = nrun[wv];
    const bool fb = NR > RCAP;                         // overflow -> full sweep
    if (fb) NR = 1;
#pragma unroll 1
    for (int ri = 0; ri < NR; ++ri) {
        u32 s = fb ? 0u : runS[wv][ri];
        u32 e = fb ? (u32)NPTS : runE[wv][ri];
        for (u32 j = s + lane; j < e; j += 64) {
            float4 p = pts4[j];
            float sc = fmaf(p.x, cx, fmaf(p.y, cy, fmaf(p.z, cz, p.w)));
            if (sc >= th) {
                int slot = atomicAdd(&lcnt[wv], 1);
                if (slot < CAP) lbuf[wv][slot] = make_float2(sc, __int_as_float(pid[j]));
            }
        }
    }
    __syncthreads();

    // ---- merge phase (proven body, candidates from LDS) -------------------
    int n = lcnt[wv];
    n = n < CAP ? n : CAP;

    float2 e0 = lbuf[wv][lane];
    float2 e1 = lbuf[wv][64 + lane];
    int id0 = __float_as_int(e0.y), id1 = __float_as_int(e1.y);

    unsigned long long k0 = mkkey(e0.x, id0, lane < n);
    unsigned long long k1 = mkkey(e1.x, id1, lane + 64 < n);

    int sel = -1;
    unsigned long long kl = k0 > k1 ? k0 : k1;
#pragma unroll
    for (int j = 0; j < KMER; ++j) {
        unsigned long long m = kl;
#pragma unroll
        for (int off = 1; off < 64; off <<= 1) {
            unsigned long long o = __shfl_xor(m, off);
            m = m > o ? m : o;
        }
        bool win = (kl == m) && (m != 0ull);
        int wid = (k0 >= k1) ? id0 : id1;
        unsigned long long wmask = __ballot(win);
        int wl = __ffsll(wmask) - 1;
        int bid = __shfl(wid, wl & 63);
        if (m == 0ull) bid = -1;
        if (lane == j) sel = bid;
        if (win) {
            if (k0 >= k1) k0 = 0ull; else k1 = 0ull;
            kl = k0 > k1 ? k0 : k1;
        }
    }

    float ox = ro[3 * ray + 0], oy = ro[3 * ray + 1], oz = ro[3 * ray + 2];
    float dx = rd[3 * ray + 0], dy = rd[3 * ray + 1], dz = rd[3 * ray + 2];
    float cxf, cyf, czf;
    {
#pragma clang fp contract(off)
        cxf = ox + dx * 3.0f;
        cyf = oy + dy * 3.0f;
        czf = oz + dz * 3.0f;
    }
    double Cx = (double)cxf, Cy = (double)cyf, Cz = (double)czf;
    double cn = Cx * Cx + Cy * Cy + Cz * Cz;

    bool valid = (lane < KMER) && (sel >= 0);
    int pidv = valid ? sel : 0;
    double X = (double)xyz[3 * pidv + 0];
    double Y = (double)xyz[3 * pidv + 1];
    double Z = (double)xyz[3 * pidv + 2];
    double sq = valid ? (cn + (X * X + Y * Y + Z * Z) - 2.0 * (Cx * X + Cy * Y + Cz * Z))
                      : (double)INFINITY;
    int cid = valid ? sel : 0x7fffffff;

    int rank = 0;
#pragma unroll
    for (int k = 0; k < KMER; ++k) {
        double sk = __shfl(sq, k);
        int    ik = __shfl(cid, k);
        if ((sk < sq) || (sk == sq && ik < cid)) ++rank;
    }

    bool take = valid && (rank < KTOP);
    float w = 0.0f, rr = 0.0f, gg = 0.0f, bb = 0.0f;
    if (take) {
        float dd = sqrtf(fmaxf((float)sq, 0.0f));
        w  = expf(-0.1f * dd) * sigm(opac[pidv]);
        rr = w * sigm(fdc[3 * pidv + 0]);
        gg = w * sigm(fdc[3 * pidv + 1]);
        bb = w * sigm(fdc[3 * pidv + 2]);
    }
#pragma unroll
    for (int off = 1; off < 64; off <<= 1) {
        w  += __shfl_xor(w,  off);
        rr += __shfl_xor(rr, off);
        gg += __shfl_xor(gg, off);
        bb += __shfl_xor(bb, off);
    }
    if (lane == 0) {
        float inv = 1.0f / (w + 1e-8f);
        out[3 * ray + 0] = rr * inv;
        out[3 * ray + 1] = gg * inv;
        out[3 * ray + 2] = bb * inv;
    }
}

// ---------------------------------------------------------------------------
extern "C" void kernel_launch(void* const* d_in, const int* in_sizes, int n_in,
                              void* d_out, int out_size, void* d_ws, size_t ws_size,
                              hipStream_t stream) {
    const float* rays_o = (const float*)d_in[0];
    const float* rays_d = (const float*)d_in[1];
    const float* xyz    = (const float*)d_in[2];
    const float* fdc    = (const float*)d_in[3];
    const float* opac   = (const float*)d_in[4];
    float* out = (float*)d_out;

    // ws layout (16B-aligned chain), total ~3.3 MB:
    char* p = (char*)d_ws;
    float4* c4       = (float4*)p;  p += (size_t)NRAYS  * 16;          // 64 KB
    float4* pts4     = (float4*)p;  p += (size_t)(NPTS + 64) * 16;     // 1.6 MB
    u32*    mat      = (u32*)p;     p += (size_t)NB * GCELLS * 4;      // 1 MB
    u32*    colsum   = (u32*)p;     p += (size_t)GCELLS * 4;           // 16 KB
    u32*    cellstart= (u32*)p;     p += (size_t)4112 * 4;             // 16.4 KB
    int*    pid      = (int*)p;     p += (size_t)(NPTS + 64) * 4;      // 400 KB
    u16*    cid16    = (u16*)p;     p += (size_t)(NPTS + 64) * 2;      // 200 KB

    theta_hist_kernel<<<NRAYS / TRAYS, 256, 0, stream>>>(xyz, rays_o, rays_d, c4, mat, cid16);
    colprefix_kernel<<<GCELLS / 256, 256, 0, stream>>>(mat, colsum);
    prefix_kernel<<<1, 256, 0, stream>>>(colsum, cellstart);
    scatter_kernel<<<NB, 256, 0, stream>>>(xyz, cid16, mat, cellstart, pts4, pid);
    scanmerge_kernel<<<NRAYS / 4, 256, 0, stream>>>(pts4, pid, cellstart, c4,
                                                    rays_o, rays_d, xyz, fdc, opac, out);
}